// Round 5
// baseline (281.862 us; speedup 1.0000x reference)
//
#include <hip/hip_runtime.h>

#define NB 8
#define NH 56
#define NW 56
#define NHW 3136          // NH*NW
#define NCHW 802816
#define NPIX 25088        // NB*NHW
#define NHP 58            // padded dim
#define EPSV 1e-5f
#define BUFS 20480        // shorts per LDS buffer: Al 4096 | Bl 16384

typedef float f32x4 __attribute__((ext_vector_type(4)));
typedef __bf16 bf16x8 __attribute__((ext_vector_type(8)));

__device__ __forceinline__ unsigned short f2b(float f) {   // RNE (epilogues)
  unsigned int u = __float_as_uint(f);
  u += 0x7FFFu + ((u >> 16) & 1u);
  return (unsigned short)(u >> 16);
}
__device__ __forceinline__ float blo(unsigned int u){ return __uint_as_float(u << 16); }
__device__ __forceinline__ float bhi(unsigned int u){ return __uint_as_float(u & 0xFFFF0000u); }
// pack 2 fp32 -> 2 bf16 (truncation) in ONE v_perm
__device__ __forceinline__ unsigned int pack_trunc(float f0, float f1) {
  return __builtin_amdgcn_perm(__float_as_uint(f1), __float_as_uint(f0), 0x07060302u);
}
// barrier WITHOUT vmcnt drain: ds ops visible (lgkmcnt 0), prefetch loads stay in flight
__device__ __forceinline__ void soft_barrier() {
  __builtin_amdgcn_s_waitcnt(0xC07F);   // vmcnt=63, expcnt=7, lgkmcnt=0
  __builtin_amdgcn_s_barrier();
}

// ---------------------------------------------------------------------------
// P0: zero the 1px borders of xbp and t1b
// ---------------------------------------------------------------------------
__global__ __launch_bounds__(256) void clear_borders(
    unsigned short* __restrict__ xbp, unsigned short* __restrict__ t1b)
{
  int i = blockIdx.x*256 + threadIdx.x;        // 58368 exact
  int q = i & 31; int pid = i >> 5;
  int b = pid / 228, j = pid % 228;
  int y, x;
  if (j < 58)       { y = 0;  x = j; }
  else if (j < 116) { y = 57; x = j - 58; }
  else { int jj = j - 116; y = 1 + (jj >> 1); x = (jj & 1) * 57; }
  size_t addr = ((size_t)(b*NHP + y)*NHP + x)*256 + q*8;
  uint4 z = make_uint4(0u,0u,0u,0u);
  *(uint4*)(xbp + addr) = z;
  *(uint4*)(t1b + addr) = z;
}

// ---------------------------------------------------------------------------
// P1: x NCHW fp32 -> xbp padded NHWC bf16 (interior only)
// ---------------------------------------------------------------------------
__global__ __launch_bounds__(256) void prep_x(
    const float* __restrict__ x, unsigned short* __restrict__ xbp)
{
  __shared__ float T[64][65];
  const int pxt  = blockIdx.x * 64;       // never crosses b (3136 = 49*64)
  const int cg   = blockIdx.y * 64;
  const int b    = pxt / NHW;
  const int rem0 = pxt % NHW;
  const int t    = threadIdx.x;
  const int pl   = t & 63;
  const int c0   = t >> 6;
  const float* src = x + (size_t)b*NCHW + rem0;
  #pragma unroll
  for (int it = 0; it < 16; ++it) {
    int c = c0 + it*4;
    T[c][pl] = src[(size_t)(cg + c)*NHW + pl];
  }
  __syncthreads();
  const int pr = t >> 5;
  const int cp = t & 31;
  #pragma unroll
  for (int it = 0; it < 8; ++it) {
    int pxl = pr + it*8;
    int rem = rem0 + pxl;
    int ho = rem / NW, wo = rem % NW;
    unsigned int pk = ((unsigned int)f2b(T[cp*2+1][pxl]) << 16) | (unsigned int)f2b(T[cp*2][pxl]);
    *(unsigned int*)(xbp + ((size_t)(b*NHP + ho + 1)*NHP + (wo + 1))*256 + cg + cp*2) = pk;
  }
}

// ---------------------------------------------------------------------------
// P2: w [co][ci][3][3] fp32 -> wp [co][k*256+ci] bf16
// ---------------------------------------------------------------------------
__global__ __launch_bounds__(256) void prep_w(
    const float* __restrict__ w, unsigned short* __restrict__ wp)
{
  int i = blockIdx.x*256 + threadIdx.x;    // 589824 exact
  int co = i / 2304;
  int r  = i % 2304;
  int k  = r >> 8;
  int ci = r & 255;
  wp[i] = f2b(w[((size_t)co*256 + ci)*9 + k]);
}

// P3: off_w [18][256][3][3] -> w3p [32 rows][k*256+ci] bf16, rows 18..31 = 0
__global__ __launch_bounds__(256) void prep_w3(
    const float* __restrict__ ow, unsigned short* __restrict__ w3p)
{
  int i = blockIdx.x*256 + threadIdx.x;    // 73728 exact
  int co = i / 2304;
  int r  = i % 2304;
  int k  = r >> 8;
  int ci = r & 255;
  w3p[i] = (co < 18) ? f2b(ow[((size_t)co*256 + ci)*9 + k]) : (unsigned short)0;
}

// ---------------------------------------------------------------------------
// GEMM1: conv3x3 + BN + ReLU -> t1b padded NHWC bf16
// BM=64 BN=256 BK=64, 512 thr = 8 waves (2M x 4N); grid 392, batch-per-XCD
// LDS dbuf + DEPTH-2 register ping-pong staging: loads issued at round r are
// consumed (written to LDS) at round r+2 -> ~1.5 rounds of latency cover.
// Round: MFMA(cur) -> write set(r+1) -> issue r+3 into same set -> soft barrier
// ---------------------------------------------------------------------------
__global__ __launch_bounds__(512, 4) void gemm_conv1(
    const unsigned short* __restrict__ xbp, const unsigned short* __restrict__ w1p,
    const float* __restrict__ gam, const float* __restrict__ bet,
    const float* __restrict__ mu,  const float* __restrict__ var,
    unsigned short* __restrict__ t1b)
{
  __shared__ unsigned short SMEM[2*BUFS];    // 80KB: two of (Al 4096 | Bl 16384)

  const int bx   = blockIdx.x;
  const int nbx  = (bx & 7)*49 + (bx >> 3);   // 392 = 8*49, batch-per-XCD
  const int m0   = nbx * 64;
  const int t    = threadIdx.x;
  const int lane = t & 63;
  const int wv   = t >> 6;
  const int wvM  = wv & 1;
  const int wvN  = wv >> 1;
  const int quad = lane >> 4;
  const int l15  = lane & 15;

  const int srow = t >> 3;     // 0..63
  const int seg  = t & 7;
  const int sxor = srow & 7;
  const int px  = m0 + srow;
  const int b   = px / NHW, rem = px % NHW;
  const int ho  = rem / NW, wo = rem % NW;
  const unsigned int pbase = ((unsigned int)(b*NHP + ho)*NHP + wo)*256u + seg*8u;

  f32x4 acc[2][4];
  #pragma unroll
  for (int i = 0; i < 2; ++i)
    #pragma unroll
    for (int j = 0; j < 4; ++j) acc[i][j] = (f32x4)(0.f);

  // two staging sets: sa (odd-round writes), sb (even-round writes)
  uint4 saA, saB0, saB1, saB2, saB3;
  uint4 sbA, sbB0, sbB1, sbB2, sbB3;

#define C1_ISSUE(SA_, SB0_, SB1_, SB2_, SB3_, RN) {                       \
    const int kn_ = (RN) >> 2, cicn_ = (RN) & 3;                          \
    const int kyn_ = kn_/3, kxn_ = kn_ - kyn_*3;                          \
    SA_  = *(const uint4*)(xbp + pbase + (unsigned int)((kyn_*NHP + kxn_)*256 + cicn_*64)); \
    const unsigned int rb_ = (unsigned int)((RN)*64) + seg*8u;            \
    SB0_ = *(const uint4*)(w1p + (size_t)(srow      )*2304 + rb_);        \
    SB1_ = *(const uint4*)(w1p + (size_t)(srow +  64)*2304 + rb_);        \
    SB2_ = *(const uint4*)(w1p + (size_t)(srow + 128)*2304 + rb_);        \
    SB3_ = *(const uint4*)(w1p + (size_t)(srow + 192)*2304 + rb_);        \
  }

  {   // prologue: r=0 direct to buf0; r=1 -> sb; r=2 -> sa
    uint4 tA, tB0, tB1, tB2, tB3;
    C1_ISSUE(tA, tB0, tB1, tB2, tB3, 0);
    *(uint4*)(&SMEM[srow*64 + ((seg ^ sxor)*8)]) = tA;
    *(uint4*)(&SMEM[4096 + (srow      )*64 + ((seg ^ sxor)*8)]) = tB0;
    *(uint4*)(&SMEM[4096 + (srow +  64)*64 + ((seg ^ sxor)*8)]) = tB1;
    *(uint4*)(&SMEM[4096 + (srow + 128)*64 + ((seg ^ sxor)*8)]) = tB2;
    *(uint4*)(&SMEM[4096 + (srow + 192)*64 + ((seg ^ sxor)*8)]) = tB3;
    C1_ISSUE(sbA, sbB0, sbB1, sbB2, sbB3, 1);
    C1_ISSUE(saA, saB0, saB1, saB2, saB3, 2);
    soft_barrier();
  }

#define C1_ROUND(R, SA_, SB0_, SB1_, SB2_, SB3_) {                        \
    const int r_ = (R);                                                   \
    unsigned short* Ac = SMEM + (r_ & 1)*BUFS;                            \
    unsigned short* Bc = Ac + 4096;                                       \
    unsigned short* An = SMEM + ((r_ + 1) & 1)*BUFS;                      \
    unsigned short* Bn = An + 4096;                                       \
    _Pragma("unroll")                                                     \
    for (int kk = 0; kk < 2; ++kk) {                                      \
      const int s8 = (kk*4 + quad) ^ (l15 & 7);                           \
      bf16x8 af[2], bfr[4];                                               \
      _Pragma("unroll")                                                   \
      for (int mt = 0; mt < 2; ++mt)                                      \
        af[mt] = *(const bf16x8*)(&Ac[(wvM*32 + mt*16 + l15)*64 + s8*8]); \
      _Pragma("unroll")                                                   \
      for (int nt = 0; nt < 4; ++nt)                                      \
        bfr[nt] = *(const bf16x8*)(&Bc[(wvN*64 + nt*16 + l15)*64 + s8*8]);\
      _Pragma("unroll")                                                   \
      for (int mt = 0; mt < 2; ++mt)                                      \
        _Pragma("unroll")                                                 \
        for (int nt = 0; nt < 4; ++nt)                                    \
          acc[mt][nt] = __builtin_amdgcn_mfma_f32_16x16x32_bf16(af[mt], bfr[nt], acc[mt][nt], 0, 0, 0); \
    }                                                                     \
    *(uint4*)(&An[srow*64 + ((seg ^ sxor)*8)]) = SA_;                     \
    *(uint4*)(&Bn[(srow      )*64 + ((seg ^ sxor)*8)]) = SB0_;            \
    *(uint4*)(&Bn[(srow +  64)*64 + ((seg ^ sxor)*8)]) = SB1_;            \
    *(uint4*)(&Bn[(srow + 128)*64 + ((seg ^ sxor)*8)]) = SB2_;            \
    *(uint4*)(&Bn[(srow + 192)*64 + ((seg ^ sxor)*8)]) = SB3_;            \
    const int rn_ = (r_ < 33) ? r_ + 3 : 35;                              \
    C1_ISSUE(SA_, SB0_, SB1_, SB2_, SB3_, rn_);                           \
    soft_barrier();                                                       \
  }

  for (int r = 0; r < 36; r += 2) {
    C1_ROUND(r,     sbA, sbB0, sbB1, sbB2, sbB3);   // even round writes r+1 (in sb)
    C1_ROUND(r + 1, saA, saB0, saB1, saB2, saB3);   // odd  round writes r+1 (in sa)
  }
#undef C1_ROUND
#undef C1_ISSUE

  // epilogue: BN+ReLU -> per-wave bounce (32px x 72 shorts) -> padded t1b
  __syncthreads();
  unsigned short* Sw = SMEM + wv*2304;
  #pragma unroll
  for (int nt = 0; nt < 4; ++nt) {
    const int co = wvN*64 + nt*16 + l15;
    const float inv  = gam[co] * rsqrtf(var[co] + EPSV);
    const float beta = bet[co] - mu[co]*inv;
    #pragma unroll
    for (int mt = 0; mt < 2; ++mt) {
      #pragma unroll
      for (int rr = 0; rr < 4; ++rr) {
        const int pxl = mt*16 + quad*4 + rr;
        float val = acc[mt][nt][rr]*inv + beta;
        val = val > 0.f ? val : 0.f;
        Sw[pxl*72 + nt*16 + l15] = f2b(val);
      }
    }
  }
  #pragma unroll
  for (int i = 0; i < 4; ++i) {
    const int pxl = (lane >> 3) + 8*i;
    const int sc  = lane & 7;
    uint4 q = *(const uint4*)(&Sw[pxl*72 + sc*8]);
    const int pg = m0 + wvM*32 + pxl;
    const int bb = pg / NHW, rm = pg % NHW;
    const int hh = rm / NW, ww = rm % NW;
    *(uint4*)(t1b + ((size_t)(bb*NHP + hh + 1)*NHP + ww + 1)*256 + wvN*64 + sc*8) = q;
  }
}

// ---------------------------------------------------------------------------
// GEMM-OFF: offset conv, split-K x4 (9 rounds each), atomicAdd into toff
// ---------------------------------------------------------------------------
__global__ __launch_bounds__(256, 8) void gemm_off(
    const unsigned short* __restrict__ t1b, const unsigned short* __restrict__ w3p,
    const float* __restrict__ ob, float* __restrict__ toff)
{
  __shared__ unsigned short Al[4096];   // 64x64
  __shared__ unsigned short Bl[2048];   // 32x64

  const int bx  = blockIdx.x;
  const int nbx = (bx & 7)*49 + (bx >> 3);
  const int m0  = nbx * 64;
  const int kc = blockIdx.y;            // K chunk 0..3
  const int t    = threadIdx.x;
  const int lane = t & 63;
  const int wv   = t >> 6;
  const int quad = lane >> 4;
  const int l15  = lane & 15;

  const int arow = t >> 2;      // 0..63
  const int as4  = t & 3;
  const int axor = arow & 7;
  const int pxa  = m0 + arow;
  const int ba   = pxa / NHW, rema = pxa % NHW;
  const unsigned int pbase = ((unsigned int)(ba*NHP + rema/NW)*NHP + rema%NW)*256u;

  const int brow = t >> 3;      // 0..31
  const int bs   = t & 7;

  f32x4 acc[2];
  #pragma unroll
  for (int nt = 0; nt < 2; ++nt) {
    float init = 0.f;
    if (kc == 0) { int co = nt*16 + l15; init = (co < 18) ? ob[co] : 0.f; }
    acc[nt] = (f32x4)(init);
  }

  uint4 pA0, pA1, pB;
  {   // prefetch first round r = kc*9
    const int r = kc*9, k = r >> 2, cic = r & 3;
    const int ky = k/3, kx = k - ky*3;
    const unsigned int base = pbase + (unsigned int)((ky*NHP + kx)*256 + cic*64);
    pA0 = *(const uint4*)(t1b + base + as4*8);
    pA1 = *(const uint4*)(t1b + base + (as4+4)*8);
    pB  = *(const uint4*)(w3p + (size_t)brow*2304 + r*64 + bs*8);
  }

  for (int rr = 0; rr < 9; ++rr) {
    const int r = kc*9 + rr;
    __syncthreads();
    *(uint4*)(&Al[arow*64 + ((as4     ^ axor)*8)]) = pA0;
    *(uint4*)(&Al[arow*64 + (((as4+4) ^ axor)*8)]) = pA1;
    *(uint4*)(&Bl[brow*64 + ((bs ^ (brow & 7))*8)]) = pB;
    {
      const int rn = (rr < 8) ? r + 1 : r;
      const int kn = rn >> 2, cicn = rn & 3;
      const int kyn = kn/3, kxn = kn - kyn*3;
      const unsigned int base = pbase + (unsigned int)((kyn*NHP + kxn)*256 + cicn*64);
      pA0 = *(const uint4*)(t1b + base + as4*8);
      pA1 = *(const uint4*)(t1b + base + (as4+4)*8);
      pB  = *(const uint4*)(w3p + (size_t)brow*2304 + rn*64 + bs*8);
    }
    soft_barrier();
    #pragma unroll
    for (int kk = 0; kk < 2; ++kk) {
      const int s8 = (kk*4 + quad) ^ (l15 & 7);
      bf16x8 af = *(const bf16x8*)(&Al[(wv*16 + l15)*64 + s8*8]);
      #pragma unroll
      for (int nt = 0; nt < 2; ++nt) {
        bf16x8 bfr = *(const bf16x8*)(&Bl[(nt*16 + l15)*64 + s8*8]);
        acc[nt] = __builtin_amdgcn_mfma_f32_16x16x32_bf16(af, bfr, acc[nt], 0, 0, 0);
      }
    }
  }
  #pragma unroll
  for (int nt = 0; nt < 2; ++nt) {
    const int co = nt*16 + l15;
    if (co < 18) {
      #pragma unroll
      for (int rr2 = 0; rr2 < 4; ++rr2) {
        const int pg = m0 + wv*16 + quad*4 + rr2;
        const int bb = pg / NHW, rm = pg % NHW;
        atomicAdd(&toff[(size_t)bb*(18*NHW) + (size_t)co*NHW + rm], acc[nt][rr2]);
      }
    }
  }
}

// ---------------------------------------------------------------------------
// GEMM2: deform_conv + BN + residual + ReLU -> out NCHW fp32
// BM=64 BN=256 BK=64, 512 thr; LDS dbuf + depth-2 corner ping-pong (per-set
// bilinear weights captured at issue), B depth-1 issued AFTER older corners.
// Round: MFMA(cur) -> pack set(r+1)+write B -> issue B(r+2), corners(r+3) -> bar
// ---------------------------------------------------------------------------
__global__ __launch_bounds__(512, 4) void gemm_deform(
    const unsigned short* __restrict__ t1b, const unsigned short* __restrict__ w2p,
    const float* __restrict__ toff, const float* __restrict__ xres,
    const float* __restrict__ gam, const float* __restrict__ bet,
    const float* __restrict__ mu,  const float* __restrict__ var,
    float* __restrict__ outp)
{
  __shared__ unsigned short SMEM[2*BUFS];    // 80KB

  const int bid  = blockIdx.x;
  const int nb   = (bid & 7)*49 + (bid >> 3);   // 392 = 8*49
  const int m0   = nb * 64;
  const int t    = threadIdx.x;
  const int lane = t & 63;
  const int wv   = t >> 6;
  const int wvM  = wv & 1;
  const int wvN  = wv >> 1;
  const int quad = lane >> 4;
  const int l15  = lane & 15;

  const int srow = t >> 3;     // 0..63
  const int seg  = t & 7;
  const int sxor = srow & 7;
  const int px   = m0 + srow;
  const int b    = px / NHW, rem = px % NHW;
  const int ho   = rem / NW, wo = rem % NW;
  const int obb  = b*(18*NHW) + rem;
  const unsigned int prowb = (unsigned int)(b*NHP);

  f32x4 acc[2][4];
  #pragma unroll
  for (int i = 0; i < 2; ++i)
    #pragma unroll
    for (int j = 0; j < 4; ++j) acc[i][j] = (f32x4)(0.f);

  // bilinear coord state for the NEWEST k (used only at issue time)
  unsigned int o00, o01, o10, o11;
  float w00, w01, w10, w11;
#define COORDS(KK) {                                                   \
    const int ky_ = (KK)/3, kx_ = (KK) - ky_*3;                        \
    const float offy = toff[obb + (KK)*NHW];                           \
    const float offx = toff[obb + (9+(KK))*NHW];                       \
    const float yf = (float)(ho - 1 + ky_) + offy;                     \
    const float xf = (float)(wo - 1 + kx_) + offx;                     \
    const float y0f = floorf(yf), x0f = floorf(xf);                    \
    const float ty = yf - y0f,   tx = xf - x0f;                        \
    const int y0p = (int)y0f + 1, x0p = (int)x0f + 1;                  \
    const int cy0 = min(max(y0p,   0), NHP-1);                         \
    const int cy1 = min(max(y0p+1, 0), NHP-1);                         \
    const int cx0 = min(max(x0p,   0), NHP-1);                         \
    const int cx1 = min(max(x0p+1, 0), NHP-1);                         \
    w00 = (1.f-ty)*(1.f-tx);  w01 = (1.f-ty)*tx;                       \
    w10 = ty*(1.f-tx);        w11 = ty*tx;                             \
    o00 = ((prowb + cy0)*NHP + cx0)*256u + seg*8u;                     \
    o01 = ((prowb + cy0)*NHP + cx1)*256u + seg*8u;                     \
    o10 = ((prowb + cy1)*NHP + cx0)*256u + seg*8u;                     \
    o11 = ((prowb + cy1)*NHP + cx1)*256u + seg*8u;                     \
  }

// bilinear-combine 4 corner uint4 with weights -> one uint4 row -> LDS dest
#define PACKW(C00,C01,C10,C11,W00,W01,W10,W11,DST) {                            \
    uint4 res;                                                                  \
    { float a0 = W00*blo(C00.x) + W01*blo(C01.x) + W10*blo(C10.x) + W11*blo(C11.x); \
      float a1 = W00*bhi(C00.x) + W01*bhi(C01.x) + W10*bhi(C10.x) + W11*bhi(C11.x); \
      res.x = pack_trunc(a0, a1); }                                             \
    { float a0 = W00*blo(C00.y) + W01*blo(C01.y) + W10*blo(C10.y) + W11*blo(C11.y); \
      float a1 = W00*bhi(C00.y) + W01*bhi(C01.y) + W10*bhi(C10.y) + W11*bhi(C11.y); \
      res.y = pack_trunc(a0, a1); }                                             \
    { float a0 = W00*blo(C00.z) + W01*blo(C01.z) + W10*blo(C10.z) + W11*blo(C11.z); \
      float a1 = W00*bhi(C00.z) + W01*bhi(C01.z) + W10*bhi(C10.z) + W11*bhi(C11.z); \
      res.z = pack_trunc(a0, a1); }                                             \
    { float a0 = W00*blo(C00.w) + W01*blo(C01.w) + W10*blo(C10.w) + W11*blo(C11.w); \
      float a1 = W00*bhi(C00.w) + W01*bhi(C01.w) + W10*bhi(C10.w) + W11*bhi(C11.w); \
      res.w = pack_trunc(a0, a1); }                                             \
    *(uint4*)(&(DST)[srow*64 + ((seg ^ sxor)*8)]) = res;                        \
  }

// issue corner loads for round RN into a set; capture current weights into set
#define ISSUEC(C00,C01,C10,C11,W00,W01,W10,W11,RN) {                            \
    const unsigned int cio_ = (unsigned int)(((RN) & 3)*64);                    \
    C00 = *(const uint4*)(t1b + o00 + cio_);                                    \
    C01 = *(const uint4*)(t1b + o01 + cio_);                                    \
    C10 = *(const uint4*)(t1b + o10 + cio_);                                    \
    C11 = *(const uint4*)(t1b + o11 + cio_);                                    \
    W00 = w00; W01 = w01; W10 = w10; W11 = w11;                                 \
  }

#define ISSUEB(RN) {                                                            \
    const unsigned int rb_ = (unsigned int)((RN)*64) + seg*8u;                  \
    pB0 = *(const uint4*)(w2p + (size_t)(srow      )*2304 + rb_);               \
    pB1 = *(const uint4*)(w2p + (size_t)(srow +  64)*2304 + rb_);               \
    pB2 = *(const uint4*)(w2p + (size_t)(srow + 128)*2304 + rb_);               \
    pB3 = *(const uint4*)(w2p + (size_t)(srow + 192)*2304 + rb_);               \
  }

  // staging sets: ca/cwa packed at ODD rounds, cb/cwb at EVEN rounds
  uint4 ca00, ca01, ca10, ca11, cb00, cb01, cb10, cb11;
  float cwa00, cwa01, cwa10, cwa11, cwb00, cwb01, cwb10, cwb11;
  uint4 pB0, pB1, pB2, pB3;

  COORDS(0);
  {   // prologue: r=0 pack direct to buf0; r=1 -> cb; r=2 -> ca; B(1) in pB
    uint4 t00, t01, t10, t11;
    t00 = *(const uint4*)(t1b + o00);
    t01 = *(const uint4*)(t1b + o01);
    t10 = *(const uint4*)(t1b + o10);
    t11 = *(const uint4*)(t1b + o11);
    ISSUEB(0);
    PACKW(t00, t01, t10, t11, w00, w01, w10, w11, SMEM);
    *(uint4*)(&SMEM[4096 + (srow      )*64 + ((seg ^ sxor)*8)]) = pB0;
    *(uint4*)(&SMEM[4096 + (srow +  64)*64 + ((seg ^ sxor)*8)]) = pB1;
    *(uint4*)(&SMEM[4096 + (srow + 128)*64 + ((seg ^ sxor)*8)]) = pB2;
    *(uint4*)(&SMEM[4096 + (srow + 192)*64 + ((seg ^ sxor)*8)]) = pB3;
    ISSUEC(cb00, cb01, cb10, cb11, cwb00, cwb01, cwb10, cwb11, 1);
    ISSUEB(1);
    ISSUEC(ca00, ca01, ca10, ca11, cwa00, cwa01, cwa10, cwa11, 2);
    soft_barrier();
  }

#define DROUND(R, C00,C01,C10,C11, W00,W01,W10,W11) {                           \
    const int r_ = (R);                                                         \
    unsigned short* Ac = SMEM + (r_ & 1)*BUFS;                                  \
    unsigned short* Bc = Ac + 4096;                                             \
    unsigned short* An = SMEM + ((r_ + 1) & 1)*BUFS;                            \
    unsigned short* Bn = An + 4096;                                             \
    if ((r_ & 3) == 1 && r_ < 33) COORDS((r_ + 3) >> 2);                        \
    _Pragma("unroll")                                                           \
    for (int kk = 0; kk < 2; ++kk) {                                            \
      const int s8 = (kk*4 + quad) ^ (l15 & 7);                                 \
      bf16x8 af[2], bfr[4];                                                     \
      _Pragma("unroll")                                                         \
      for (int mt = 0; mt < 2; ++mt)                                            \
        af[mt] = *(const bf16x8*)(&Ac[(wvM*32 + mt*16 + l15)*64 + s8*8]);       \
      _Pragma("unroll")                                                         \
      for (int nt = 0; nt < 4; ++nt)                                            \
        bfr[nt] = *(const bf16x8*)(&Bc[(wvN*64 + nt*16 + l15)*64 + s8*8]);      \
      _Pragma("unroll")                                                         \
      for (int mt = 0; mt < 2; ++mt)                                            \
        _Pragma("unroll")                                                       \
        for (int nt = 0; nt < 4; ++nt)                                          \
          acc[mt][nt] = __builtin_amdgcn_mfma_f32_16x16x32_bf16(af[mt], bfr[nt], acc[mt][nt], 0, 0, 0); \
    }                                                                           \
    PACKW(C00, C01, C10, C11, W00, W01, W10, W11, An);                          \
    *(uint4*)(&Bn[(srow      )*64 + ((seg ^ sxor)*8)]) = pB0;                   \
    *(uint4*)(&Bn[(srow +  64)*64 + ((seg ^ sxor)*8)]) = pB1;                   \
    *(uint4*)(&Bn[(srow + 128)*64 + ((seg ^ sxor)*8)]) = pB2;                   \
    *(uint4*)(&Bn[(srow + 192)*64 + ((seg ^ sxor)*8)]) = pB3;                   \
    const int rnB_ = (r_ < 34) ? r_ + 2 : 35;                                   \
    ISSUEB(rnB_);                                                               \
    const int rn3_ = (r_ < 33) ? r_ + 3 : 35;                                   \
    ISSUEC(C00, C01, C10, C11, W00, W01, W10, W11, rn3_);                       \
    soft_barrier();                                                             \
  }

  for (int r = 0; r < 36; r += 2) {
    DROUND(r,     cb00, cb01, cb10, cb11, cwb00, cwb01, cwb10, cwb11);  // even
    DROUND(r + 1, ca00, ca01, ca10, ca11, cwa00, cwa01, cwa10, cwa11);  // odd
  }
#undef DROUND
#undef ISSUEB
#undef ISSUEC
#undef PACKW
#undef COORDS

  // epilogue: per-wave f32 bounce (32px x 33), 2 co-halves -> coalesced NCHW
  __syncthreads();
  float* Sl = (float*)SMEM + wv*1056;
  const int pxl_r = lane & 31;
  const int csel  = lane >> 5;
  const int pg    = m0 + wvM*32 + pxl_r;
  const int bo    = pg / NHW, remo = pg % NHW;
  const size_t obase = (size_t)bo*NCHW + remo;
  #pragma unroll
  for (int h = 0; h < 2; ++h) {
    #pragma unroll
    for (int nt2 = 0; nt2 < 2; ++nt2) {
      const int nt = h*2 + nt2;
      #pragma unroll
      for (int mt = 0; mt < 2; ++mt) {
        #pragma unroll
        for (int rr = 0; rr < 4; ++rr) {
          const int pxl = mt*16 + quad*4 + rr;
          Sl[pxl*33 + nt2*16 + l15] = acc[mt][nt][rr];
        }
      }
    }
    #pragma unroll
    for (int j = 0; j < 16; ++j) {
      const int col = csel*16 + j;
      const int co  = wvN*64 + h*32 + col;
      const float inv  = gam[co] * rsqrtf(var[co] + EPSV);
      const float beta = bet[co] - mu[co]*inv;
      const size_t off = obase + (size_t)co*NHW;
      float val = Sl[pxl_r*33 + col];
      float o = val*inv + beta + xres[off];
      outp[off] = o > 0.f ? o : 0.f;
    }
  }
}

extern "C" void kernel_launch(void* const* d_in, const int* in_sizes, int n_in,
                              void* d_out, int out_size, void* d_ws, size_t ws_size,
                              hipStream_t stream) {
  const float* x   = (const float*)d_in[0];
  const float* w1  = (const float*)d_in[1];
  const float* g1  = (const float*)d_in[2];
  const float* b1  = (const float*)d_in[3];
  const float* m1  = (const float*)d_in[4];
  const float* v1  = (const float*)d_in[5];
  const float* ow  = (const float*)d_in[6];
  const float* ob  = (const float*)d_in[7];
  const float* w2  = (const float*)d_in[8];
  const float* g2  = (const float*)d_in[9];
  const float* b2  = (const float*)d_in[10];
  const float* m2  = (const float*)d_in[11];
  const float* v2  = (const float*)d_in[12];
  float* out = (float*)d_out;

  const size_t PADSZ = (size_t)NB*NHP*NHP*256;
  unsigned short* xbp = (unsigned short*)d_ws;
  unsigned short* t1b = xbp + PADSZ;
  float*          tof = (float*)(t1b + PADSZ);
  unsigned short* w1p = (unsigned short*)(tof + (size_t)NB*18*NHW);
  unsigned short* w2p = w1p + (size_t)589824;
  unsigned short* w3p = w2p + (size_t)589824;

  clear_borders<<<228, 256, 0, stream>>>(xbp, t1b);
  dim3 gp(392, 4, 1);
  prep_x<<<gp, 256, 0, stream>>>(x, xbp);
  prep_w<<<2304, 256, 0, stream>>>(w1, w1p);
  prep_w<<<2304, 256, 0, stream>>>(w2, w2p);
  prep_w3<<<288, 256, 0, stream>>>(ow, w3p);
  hipMemsetAsync(tof, 0, (size_t)NB*18*NHW*sizeof(float), stream);

  gemm_conv1<<<392, 512, 0, stream>>>(xbp, w1p, g1, b1, m1, v1, t1b);
  dim3 go(392, 4, 1);
  gemm_off<<<go, 256, 0, stream>>>(t1b, w3p, ob, tof);
  gemm_deform<<<392, 512, 0, stream>>>(t1b, w2p, tof, x, g2, b2, m2, v2, out);
}

// Round 6
// 273.384 us; speedup vs baseline: 1.0310x; 1.0310x over previous
//
#include <hip/hip_runtime.h>

#define NB 8
#define NH 56
#define NW 56
#define NHW 3136          // NH*NW
#define NCHW 802816
#define NPIX 25088        // NB*NHW
#define NHP 58            // padded dim
#define EPSV 1e-5f
#define BUFS 20480        // shorts per LDS buffer: Al 4096 | Bl 16384
#define TOFN 451584       // NB*18*NHW floats

typedef float f32x4 __attribute__((ext_vector_type(4)));
typedef __bf16 bf16x8 __attribute__((ext_vector_type(8)));

__device__ __forceinline__ unsigned short f2b(float f) {   // RNE (epilogues)
  unsigned int u = __float_as_uint(f);
  u += 0x7FFFu + ((u >> 16) & 1u);
  return (unsigned short)(u >> 16);
}
__device__ __forceinline__ float blo(unsigned int u){ return __uint_as_float(u << 16); }
__device__ __forceinline__ float bhi(unsigned int u){ return __uint_as_float(u & 0xFFFF0000u); }
// pack 2 fp32 -> 2 bf16 (truncation) in ONE v_perm
__device__ __forceinline__ unsigned int pack_trunc(float f0, float f1) {
  return __builtin_amdgcn_perm(__float_as_uint(f1), __float_as_uint(f0), 0x07060302u);
}
// barrier WITHOUT vmcnt drain: ds ops visible (lgkmcnt 0), prefetch loads stay in flight
__device__ __forceinline__ void soft_barrier() {
  __builtin_amdgcn_s_waitcnt(0xC07F);   // vmcnt=63, expcnt=7, lgkmcnt=0
  __builtin_amdgcn_s_barrier();
}

// ---------------------------------------------------------------------------
// P0: zero the 1px borders of xbp and t1b + zero tof (replaces memset launch)
// ---------------------------------------------------------------------------
__global__ __launch_bounds__(256) void clear_borders(
    unsigned short* __restrict__ xbp, unsigned short* __restrict__ t1b,
    float* __restrict__ tof)
{
  int i = blockIdx.x*256 + threadIdx.x;        // 58368 exact
  int q = i & 31; int pid = i >> 5;
  int b = pid / 228, j = pid % 228;
  int y, x;
  if (j < 58)       { y = 0;  x = j; }
  else if (j < 116) { y = 57; x = j - 58; }
  else { int jj = j - 116; y = 1 + (jj >> 1); x = (jj & 1) * 57; }
  size_t addr = ((size_t)(b*NHP + y)*NHP + x)*256 + q*8;
  uint4 z = make_uint4(0u,0u,0u,0u);
  *(uint4*)(xbp + addr) = z;
  *(uint4*)(t1b + addr) = z;
  int zi = i*8;                                // 56448*8 = 451584 exact
  if (zi < TOFN) {
    *(float4*)(tof + zi)     = make_float4(0.f,0.f,0.f,0.f);
    *(float4*)(tof + zi + 4) = make_float4(0.f,0.f,0.f,0.f);
  }
}

// ---------------------------------------------------------------------------
// P1: x NCHW fp32 -> xbp padded NHWC bf16 (interior only)
// ---------------------------------------------------------------------------
__global__ __launch_bounds__(256) void prep_x(
    const float* __restrict__ x, unsigned short* __restrict__ xbp)
{
  __shared__ float T[64][65];
  const int pxt  = blockIdx.x * 64;       // never crosses b (3136 = 49*64)
  const int cg   = blockIdx.y * 64;
  const int b    = pxt / NHW;
  const int rem0 = pxt % NHW;
  const int t    = threadIdx.x;
  const int pl   = t & 63;
  const int c0   = t >> 6;
  const float* src = x + (size_t)b*NCHW + rem0;
  #pragma unroll
  for (int it = 0; it < 16; ++it) {
    int c = c0 + it*4;
    T[c][pl] = src[(size_t)(cg + c)*NHW + pl];
  }
  __syncthreads();
  const int pr = t >> 5;
  const int cp = t & 31;
  #pragma unroll
  for (int it = 0; it < 8; ++it) {
    int pxl = pr + it*8;
    int rem = rem0 + pxl;
    int ho = rem / NW, wo = rem % NW;
    unsigned int pk = ((unsigned int)f2b(T[cp*2+1][pxl]) << 16) | (unsigned int)f2b(T[cp*2][pxl]);
    *(unsigned int*)(xbp + ((size_t)(b*NHP + ho + 1)*NHP + (wo + 1))*256 + cg + cp*2) = pk;
  }
}

// ---------------------------------------------------------------------------
// P2: all three weight preps in ONE kernel (w1 -> w1p, w2 -> w2p, ow -> w3p)
// ---------------------------------------------------------------------------
__global__ __launch_bounds__(256) void prep_w_all(
    const float* __restrict__ w1, const float* __restrict__ w2,
    const float* __restrict__ ow,
    unsigned short* __restrict__ w1p, unsigned short* __restrict__ w2p,
    unsigned short* __restrict__ w3p)
{
  int i = blockIdx.x*256 + threadIdx.x;    // 1253376 exact (4896 blocks)
  if (i < 589824) {
    int co = i / 2304, r = i % 2304, k = r >> 8, ci = r & 255;
    w1p[i] = f2b(w1[((size_t)co*256 + ci)*9 + k]);
  } else if (i < 1179648) {
    int j = i - 589824;
    int co = j / 2304, r = j % 2304, k = r >> 8, ci = r & 255;
    w2p[j] = f2b(w2[((size_t)co*256 + ci)*9 + k]);
  } else {
    int j = i - 1179648;                   // < 73728
    int co = j / 2304, r = j % 2304, k = r >> 8, ci = r & 255;
    w3p[j] = (co < 18) ? f2b(ow[((size_t)co*256 + ci)*9 + k]) : (unsigned short)0;
  }
}

// ---------------------------------------------------------------------------
// GEMM1: conv3x3 + BN + ReLU -> t1b padded NHWC bf16
// BM=64 BN=256 BK=64; 1024 thr = 16 waves (4M x 4N), wave tile 16x64; grid 392
// LDS dbuf, depth-1 reg prefetch, 1 soft barrier/round (round-4 schedule).
// 16 waves/block -> 4 waves/SIMD resident even at 1 block/CU.
// ---------------------------------------------------------------------------
__global__ __launch_bounds__(1024, 4) void gemm_conv1(
    const unsigned short* __restrict__ xbp, const unsigned short* __restrict__ w1p,
    const float* __restrict__ gam, const float* __restrict__ bet,
    const float* __restrict__ mu,  const float* __restrict__ var,
    unsigned short* __restrict__ t1b)
{
  __shared__ unsigned short SMEM[2*BUFS];    // 80KB: two of (Al 4096 | Bl 16384)

  const int bx   = blockIdx.x;
  const int nbx  = (bx & 7)*49 + (bx >> 3);   // 392 = 8*49, batch-per-XCD
  const int m0   = nbx * 64;
  const int t    = threadIdx.x;
  const int lane = t & 63;
  const int wv   = t >> 6;       // 0..15
  const int wvM  = wv & 3;       // 4 M groups of 16 rows
  const int wvN  = wv >> 2;      // 4 N groups of 64 cols
  const int quad = lane >> 4;
  const int l15  = lane & 15;

  // A staging: 64 rows x 128B, 16 thr/row, 8B (uint2) each
  const int srowA = t >> 4;      // 0..63
  const int seg15 = t & 15;
  const int aoff  = srowA*64 + (((seg15 >> 1) ^ (srowA & 7))*8 + (seg15 & 1)*4);
  // B staging: 256 rows x 128B, 4 thr/row, 2x uint4 each
  const int rowB  = t >> 2;      // 0..255
  const int bs2   = (t & 3)*2;
  const int boff0 = rowB*64 + (((bs2    ) ^ (rowB & 7))*8);
  const int boff1 = rowB*64 + (((bs2 + 1) ^ (rowB & 7))*8);

  const int px  = m0 + srowA;
  const int b   = px / NHW, rem = px % NHW;
  const int ho  = rem / NW, wo = rem % NW;
  const unsigned int pbase = ((unsigned int)(b*NHP + ho)*NHP + wo)*256u + seg15*4u;

  f32x4 acc[4];
  #pragma unroll
  for (int j = 0; j < 4; ++j) acc[j] = (f32x4)(0.f);

  uint2 pA;
  uint4 pB0, pB1;
  {   // prologue: r=0 direct to buf0; r=1 -> regs
    uint2 tA  = *(const uint2*)(xbp + pbase);
    uint4 tB0 = *(const uint4*)(w1p + (size_t)rowB*2304 + bs2*8);
    uint4 tB1 = *(const uint4*)(w1p + (size_t)rowB*2304 + bs2*8 + 8);
    *(uint2*)(&SMEM[aoff]) = tA;
    *(uint4*)(&SMEM[4096 + boff0]) = tB0;
    *(uint4*)(&SMEM[4096 + boff1]) = tB1;
    pA  = *(const uint2*)(xbp + pbase + 64u);          // r=1: k=0,cic=1
    pB0 = *(const uint4*)(w1p + (size_t)rowB*2304 + 64 + bs2*8);
    pB1 = *(const uint4*)(w1p + (size_t)rowB*2304 + 64 + bs2*8 + 8);
    soft_barrier();
  }

  for (int r = 0; r < 36; ++r) {
    unsigned short* Ac = SMEM + (r & 1)*BUFS;
    unsigned short* Bc = Ac + 4096;
    unsigned short* An = SMEM + ((r + 1) & 1)*BUFS;
    unsigned short* Bn = An + 4096;
    // write prefetched r+1 into next buffer
    *(uint2*)(&An[aoff]) = pA;
    *(uint4*)(&Bn[boff0]) = pB0;
    *(uint4*)(&Bn[boff1]) = pB1;
    {   // prefetch r+2 (clamped)
      const int rn = (r < 34) ? r + 2 : 35;
      const int kn = rn >> 2, cicn = rn & 3;
      const int kyn = kn/3, kxn = kn - kyn*3;
      pA  = *(const uint2*)(xbp + pbase + (unsigned int)((kyn*NHP + kxn)*256 + cicn*64));
      const unsigned int rb = (unsigned int)(rn*64) + bs2*8u;
      pB0 = *(const uint4*)(w1p + (size_t)rowB*2304 + rb);
      pB1 = *(const uint4*)(w1p + (size_t)rowB*2304 + rb + 8);
    }
    // MFMA from current buffer
    #pragma unroll
    for (int kk = 0; kk < 2; ++kk) {
      const int s8 = (kk*4 + quad) ^ (l15 & 7);
      bf16x8 af = *(const bf16x8*)(&Ac[(wvM*16 + l15)*64 + s8*8]);
      bf16x8 bfr[4];
      #pragma unroll
      for (int nt = 0; nt < 4; ++nt)
        bfr[nt] = *(const bf16x8*)(&Bc[(wvN*64 + nt*16 + l15)*64 + s8*8]);
      #pragma unroll
      for (int nt = 0; nt < 4; ++nt)
        acc[nt] = __builtin_amdgcn_mfma_f32_16x16x32_bf16(af, bfr[nt], acc[nt], 0, 0, 0);
    }
    soft_barrier();
  }

  // epilogue: BN+ReLU -> per-wave bounce (16px x 72 shorts) -> padded t1b
  __syncthreads();
  unsigned short* Sw = SMEM + wv*1152;    // 16*1152 = 18432 <= 40960
  #pragma unroll
  for (int nt = 0; nt < 4; ++nt) {
    const int co = wvN*64 + nt*16 + l15;
    const float inv  = gam[co] * rsqrtf(var[co] + EPSV);
    const float beta = bet[co] - mu[co]*inv;
    #pragma unroll
    for (int rr = 0; rr < 4; ++rr) {
      const int pxl = quad*4 + rr;
      float val = acc[nt][rr]*inv + beta;
      val = val > 0.f ? val : 0.f;
      Sw[pxl*72 + nt*16 + l15] = f2b(val);
    }
  }
  #pragma unroll
  for (int i = 0; i < 2; ++i) {
    const int pxl = (lane >> 3) + 8*i;    // 0..15
    const int sc  = lane & 7;
    uint4 q = *(const uint4*)(&Sw[pxl*72 + sc*8]);
    const int pg = m0 + wvM*16 + pxl;
    const int bb = pg / NHW, rm = pg % NHW;
    const int hh = rm / NW, ww = rm % NW;
    *(uint4*)(t1b + ((size_t)(bb*NHP + hh + 1)*NHP + ww + 1)*256 + wvN*64 + sc*8) = q;
  }
}

// ---------------------------------------------------------------------------
// GEMM-OFF: offset conv, split-K x4 (9 rounds each), atomicAdd into toff
// (unchanged from the verified round-4 kernel)
// ---------------------------------------------------------------------------
__global__ __launch_bounds__(256, 8) void gemm_off(
    const unsigned short* __restrict__ t1b, const unsigned short* __restrict__ w3p,
    const float* __restrict__ ob, float* __restrict__ toff)
{
  __shared__ unsigned short Al[4096];   // 64x64
  __shared__ unsigned short Bl[2048];   // 32x64

  const int bx  = blockIdx.x;
  const int nbx = (bx & 7)*49 + (bx >> 3);
  const int m0  = nbx * 64;
  const int kc = blockIdx.y;            // K chunk 0..3
  const int t    = threadIdx.x;
  const int lane = t & 63;
  const int wv   = t >> 6;
  const int quad = lane >> 4;
  const int l15  = lane & 15;

  const int arow = t >> 2;      // 0..63
  const int as4  = t & 3;
  const int axor = arow & 7;
  const int pxa  = m0 + arow;
  const int ba   = pxa / NHW, rema = pxa % NHW;
  const unsigned int pbase = ((unsigned int)(ba*NHP + rema/NW)*NHP + rema%NW)*256u;

  const int brow = t >> 3;      // 0..31
  const int bs   = t & 7;

  f32x4 acc[2];
  #pragma unroll
  for (int nt = 0; nt < 2; ++nt) {
    float init = 0.f;
    if (kc == 0) { int co = nt*16 + l15; init = (co < 18) ? ob[co] : 0.f; }
    acc[nt] = (f32x4)(init);
  }

  uint4 pA0, pA1, pB;
  {   // prefetch first round r = kc*9
    const int r = kc*9, k = r >> 2, cic = r & 3;
    const int ky = k/3, kx = k - ky*3;
    const unsigned int base = pbase + (unsigned int)((ky*NHP + kx)*256 + cic*64);
    pA0 = *(const uint4*)(t1b + base + as4*8);
    pA1 = *(const uint4*)(t1b + base + (as4+4)*8);
    pB  = *(const uint4*)(w3p + (size_t)brow*2304 + r*64 + bs*8);
  }

  for (int rr = 0; rr < 9; ++rr) {
    const int r = kc*9 + rr;
    __syncthreads();
    *(uint4*)(&Al[arow*64 + ((as4     ^ axor)*8)]) = pA0;
    *(uint4*)(&Al[arow*64 + (((as4+4) ^ axor)*8)]) = pA1;
    *(uint4*)(&Bl[brow*64 + ((bs ^ (brow & 7))*8)]) = pB;
    {
      const int rn = (rr < 8) ? r + 1 : r;
      const int kn = rn >> 2, cicn = rn & 3;
      const int kyn = kn/3, kxn = kn - kyn*3;
      const unsigned int base = pbase + (unsigned int)((kyn*NHP + kxn)*256 + cicn*64);
      pA0 = *(const uint4*)(t1b + base + as4*8);
      pA1 = *(const uint4*)(t1b + base + (as4+4)*8);
      pB  = *(const uint4*)(w3p + (size_t)brow*2304 + rn*64 + bs*8);
    }
    soft_barrier();
    #pragma unroll
    for (int kk = 0; kk < 2; ++kk) {
      const int s8 = (kk*4 + quad) ^ (l15 & 7);
      bf16x8 af = *(const bf16x8*)(&Al[(wv*16 + l15)*64 + s8*8]);
      #pragma unroll
      for (int nt = 0; nt < 2; ++nt) {
        bf16x8 bfr = *(const bf16x8*)(&Bl[(nt*16 + l15)*64 + s8*8]);
        acc[nt] = __builtin_amdgcn_mfma_f32_16x16x32_bf16(af, bfr, acc[nt], 0, 0, 0);
      }
    }
  }
  #pragma unroll
  for (int nt = 0; nt < 2; ++nt) {
    const int co = nt*16 + l15;
    if (co < 18) {
      #pragma unroll
      for (int rr2 = 0; rr2 < 4; ++rr2) {
        const int pg = m0 + wv*16 + quad*4 + rr2;
        const int bb = pg / NHW, rm = pg % NHW;
        atomicAdd(&toff[(size_t)bb*(18*NHW) + (size_t)co*NHW + rm], acc[nt][rr2]);
      }
    }
  }
}

// ---------------------------------------------------------------------------
// GEMM2: deform_conv + BN + residual + ReLU -> out NCHW fp32
// BM=64 BN=256 BK=64; 1024 thr = 16 waves (4M x 4N), wave tile 16x64; grid 392
// LDS dbuf + depth-1 corner/B prefetch, 1 soft barrier/round (round-4 schedule)
// ---------------------------------------------------------------------------
__global__ __launch_bounds__(1024, 4) void gemm_deform(
    const unsigned short* __restrict__ t1b, const unsigned short* __restrict__ w2p,
    const float* __restrict__ toff, const float* __restrict__ xres,
    const float* __restrict__ gam, const float* __restrict__ bet,
    const float* __restrict__ mu,  const float* __restrict__ var,
    float* __restrict__ outp)
{
  __shared__ unsigned short SMEM[2*BUFS];    // 80KB

  const int bid  = blockIdx.x;
  const int nb   = (bid & 7)*49 + (bid >> 3);   // 392 = 8*49
  const int m0   = nb * 64;
  const int t    = threadIdx.x;
  const int lane = t & 63;
  const int wv   = t >> 6;       // 0..15
  const int wvM  = wv & 3;
  const int wvN  = wv >> 2;
  const int quad = lane >> 4;
  const int l15  = lane & 15;

  const int srowA = t >> 4;      // 0..63
  const int seg15 = t & 15;
  const int aoff  = srowA*64 + (((seg15 >> 1) ^ (srowA & 7))*8 + (seg15 & 1)*4);
  const int rowB  = t >> 2;      // 0..255
  const int bs2   = (t & 3)*2;
  const int boff0 = rowB*64 + (((bs2    ) ^ (rowB & 7))*8);
  const int boff1 = rowB*64 + (((bs2 + 1) ^ (rowB & 7))*8);

  const int px   = m0 + srowA;
  const int b    = px / NHW, rem = px % NHW;
  const int ho   = rem / NW, wo = rem % NW;
  const int obb  = b*(18*NHW) + rem;
  const unsigned int prowb = (unsigned int)(b*NHP);

  f32x4 acc[4];
  #pragma unroll
  for (int j = 0; j < 4; ++j) acc[j] = (f32x4)(0.f);

  // bilinear coord state for the k being issued
  unsigned int o00, o01, o10, o11;
  float w00, w01, w10, w11;
#define COORDS(KK) {                                                   \
    const int ky_ = (KK)/3, kx_ = (KK) - ky_*3;                        \
    const float offy = toff[obb + (KK)*NHW];                           \
    const float offx = toff[obb + (9+(KK))*NHW];                       \
    const float yf = (float)(ho - 1 + ky_) + offy;                     \
    const float xf = (float)(wo - 1 + kx_) + offx;                     \
    const float y0f = floorf(yf), x0f = floorf(xf);                    \
    const float ty = yf - y0f,   tx = xf - x0f;                        \
    const int y0p = (int)y0f + 1, x0p = (int)x0f + 1;                  \
    const int cy0 = min(max(y0p,   0), NHP-1);                         \
    const int cy1 = min(max(y0p+1, 0), NHP-1);                         \
    const int cx0 = min(max(x0p,   0), NHP-1);                         \
    const int cx1 = min(max(x0p+1, 0), NHP-1);                         \
    w00 = (1.f-ty)*(1.f-tx);  w01 = (1.f-ty)*tx;                       \
    w10 = ty*(1.f-tx);        w11 = ty*tx;                             \
    o00 = ((prowb + cy0)*NHP + cx0)*256u + seg15*4u;                   \
    o01 = ((prowb + cy0)*NHP + cx1)*256u + seg15*4u;                   \
    o10 = ((prowb + cy1)*NHP + cx0)*256u + seg15*4u;                   \
    o11 = ((prowb + cy1)*NHP + cx1)*256u + seg15*4u;                   \
  }

// bilinear-combine 4 corner uint2 -> one uint2 (4 bf16) -> LDS dest
#define PACKW(DST) {                                                            \
    uint2 res;                                                                  \
    { float a0 = w00*blo(pc00.x) + w01*blo(pc01.x) + w10*blo(pc10.x) + w11*blo(pc11.x); \
      float a1 = w00*bhi(pc00.x) + w01*bhi(pc01.x) + w10*bhi(pc10.x) + w11*bhi(pc11.x); \
      res.x = pack_trunc(a0, a1); }                                             \
    { float a0 = w00*blo(pc00.y) + w01*blo(pc01.y) + w10*blo(pc10.y) + w11*blo(pc11.y); \
      float a1 = w00*bhi(pc00.y) + w01*bhi(pc01.y) + w10*bhi(pc10.y) + w11*bhi(pc11.y); \
      res.y = pack_trunc(a0, a1); }                                             \
    *(uint2*)(&(DST)[aoff]) = res;                                              \
  }

#define ISSUEC(RN) {                                                           \
    const unsigned int cio_ = (unsigned int)(((RN) & 3)*64);                   \
    pc00 = *(const uint2*)(t1b + o00 + cio_);                                  \
    pc01 = *(const uint2*)(t1b + o01 + cio_);                                  \
    pc10 = *(const uint2*)(t1b + o10 + cio_);                                  \
    pc11 = *(const uint2*)(t1b + o11 + cio_);                                  \
  }
#define ISSUEB(RN) {                                                           \
    const unsigned int rb_ = (unsigned int)((RN)*64) + bs2*8u;                 \
    pB0 = *(const uint4*)(w2p + (size_t)rowB*2304 + rb_);                      \
    pB1 = *(const uint4*)(w2p + (size_t)rowB*2304 + rb_ + 8);                  \
  }

  uint2 pc00, pc01, pc10, pc11;
  uint4 pB0, pB1;

  COORDS(0);
  {   // prologue: r=0 pack direct to buf0; issue r=1 into regs
    ISSUEC(0);
    ISSUEB(0);
    PACKW(SMEM);
    *(uint4*)(&SMEM[4096 + boff0]) = pB0;
    *(uint4*)(&SMEM[4096 + boff1]) = pB1;
    ISSUEC(1);
    ISSUEB(1);
    soft_barrier();
  }

  for (int r = 0; r < 36; ++r) {
    unsigned short* Ac = SMEM + (r & 1)*BUFS;
    unsigned short* Bc = Ac + 4096;
    unsigned short* An = SMEM + ((r + 1) & 1)*BUFS;
    unsigned short* Bn = An + 4096;
    // pack prefetched round r+1 corners (weights for k=(r+1)>>2 still live)
    PACKW(An);
    *(uint4*)(&Bn[boff0]) = pB0;
    *(uint4*)(&Bn[boff1]) = pB1;
    // coords for the k of round r+2 (AFTER pack used old weights)
    if ((r & 3) == 2 && r < 34) COORDS((r + 2) >> 2);
    {   // prefetch r+2 (clamped)
      const int rn = (r < 34) ? r + 2 : 35;
      ISSUEC(rn);
      ISSUEB(rn);
    }
    // MFMA from current buffer
    #pragma unroll
    for (int kk = 0; kk < 2; ++kk) {
      const int s8 = (kk*4 + quad) ^ (l15 & 7);
      bf16x8 af = *(const bf16x8*)(&Ac[(wvM*16 + l15)*64 + s8*8]);
      bf16x8 bfr[4];
      #pragma unroll
      for (int nt = 0; nt < 4; ++nt)
        bfr[nt] = *(const bf16x8*)(&Bc[(wvN*64 + nt*16 + l15)*64 + s8*8]);
      #pragma unroll
      for (int nt = 0; nt < 4; ++nt)
        acc[nt] = __builtin_amdgcn_mfma_f32_16x16x32_bf16(af, bfr[nt], acc[nt], 0, 0, 0);
    }
    soft_barrier();
  }
#undef ISSUEB
#undef ISSUEC
#undef PACKW
#undef COORDS

  // epilogue: per-wave f32 bounce (16px x 33), 2 co-halves -> coalesced NCHW
  __syncthreads();
  float* Sl = (float*)SMEM + wv*528;     // 16*528*4B = 33792B <= 81920
  const int pxl_r = lane & 15;
  const int csel  = lane >> 4;           // 0..3
  const int pg    = m0 + wvM*16 + pxl_r;
  const int bo    = pg / NHW, remo = pg % NHW;
  const size_t obase = (size_t)bo*NCHW + remo;
  #pragma unroll
  for (int h = 0; h < 2; ++h) {
    #pragma unroll
    for (int nt2 = 0; nt2 < 2; ++nt2) {
      const int nt = h*2 + nt2;
      #pragma unroll
      for (int rr = 0; rr < 4; ++rr) {
        const int pxl = quad*4 + rr;
        Sl[pxl*33 + nt2*16 + l15] = acc[nt][rr];
      }
    }
    #pragma unroll
    for (int j = 0; j < 8; ++j) {
      const int col = csel*8 + j;
      const int co  = wvN*64 + h*32 + col;
      const float inv  = gam[co] * rsqrtf(var[co] + EPSV);
      const float beta = bet[co] - mu[co]*inv;
      const size_t off = obase + (size_t)co*NHW;
      float val = Sl[pxl_r*33 + col];
      float o = val*inv + beta + xres[off];
      outp[off] = o > 0.f ? o : 0.f;
    }
  }
}

extern "C" void kernel_launch(void* const* d_in, const int* in_sizes, int n_in,
                              void* d_out, int out_size, void* d_ws, size_t ws_size,
                              hipStream_t stream) {
  const float* x   = (const float*)d_in[0];
  const float* w1  = (const float*)d_in[1];
  const float* g1  = (const float*)d_in[2];
  const float* b1  = (const float*)d_in[3];
  const float* m1  = (const float*)d_in[4];
  const float* v1  = (const float*)d_in[5];
  const float* ow  = (const float*)d_in[6];
  const float* ob  = (const float*)d_in[7];
  const float* w2  = (const float*)d_in[8];
  const float* g2  = (const float*)d_in[9];
  const float* b2  = (const float*)d_in[10];
  const float* m2  = (const float*)d_in[11];
  const float* v2  = (const float*)d_in[12];
  float* out = (float*)d_out;

  const size_t PADSZ = (size_t)NB*NHP*NHP*256;
  unsigned short* xbp = (unsigned short*)d_ws;
  unsigned short* t1b = xbp + PADSZ;
  float*          tof = (float*)(t1b + PADSZ);
  unsigned short* w1p = (unsigned short*)(tof + (size_t)NB*18*NHW);
  unsigned short* w2p = w1p + (size_t)589824;
  unsigned short* w3p = w2p + (size_t)589824;

  clear_borders<<<228, 256, 0, stream>>>(xbp, t1b, tof);
  dim3 gp(392, 4, 1);
  prep_x<<<gp, 256, 0, stream>>>(x, xbp);
  prep_w_all<<<4896, 256, 0, stream>>>(w1, w2, ow, w1p, w2p, w3p);

  gemm_conv1<<<392, 1024, 0, stream>>>(xbp, w1p, g1, b1, m1, v1, t1b);
  dim3 go(392, 4, 1);
  gemm_off<<<go, 256, 0, stream>>>(t1b, w3p, ob, tof);
  gemm_deform<<<392, 1024, 0, stream>>>(t1b, w2p, tof, x, g2, b2, m2, v2, out);
}

// Round 7
// 235.312 us; speedup vs baseline: 1.1978x; 1.1618x over previous
//
#include <hip/hip_runtime.h>

#define NB 8
#define NH 56
#define NW 56
#define NHW 3136          // NH*NW
#define NCHW 802816
#define NPIX 25088        // NB*NHW
#define NHP 58            // padded dim
#define EPSV 1e-5f
#define BUFS 20480        // shorts per LDS buffer: Al 4096 | Bl 16384
#define TOFN 451584       // NB*18*NHW floats

typedef float f32x4 __attribute__((ext_vector_type(4)));
typedef __bf16 bf16x8 __attribute__((ext_vector_type(8)));

__device__ __forceinline__ unsigned short f2b(float f) {   // RNE (epilogues)
  unsigned int u = __float_as_uint(f);
  u += 0x7FFFu + ((u >> 16) & 1u);
  return (unsigned short)(u >> 16);
}
__device__ __forceinline__ float blo(unsigned int u){ return __uint_as_float(u << 16); }
__device__ __forceinline__ float bhi(unsigned int u){ return __uint_as_float(u & 0xFFFF0000u); }
// pack 2 fp32 -> 2 bf16 (truncation) in ONE v_perm
__device__ __forceinline__ unsigned int pack_trunc(float f0, float f1) {
  return __builtin_amdgcn_perm(__float_as_uint(f1), __float_as_uint(f0), 0x07060302u);
}
// barrier WITHOUT vmcnt drain (used by gemm_off only)
__device__ __forceinline__ void soft_barrier() {
  __builtin_amdgcn_s_waitcnt(0xC07F);   // vmcnt=63, expcnt=7, lgkmcnt=0
  __builtin_amdgcn_s_barrier();
}
// async global->LDS DMA, 16B per lane; LDS dest = wave-uniform base + lane*16
__device__ __forceinline__ void dma16(const unsigned short* g, unsigned short* l) {
  __builtin_amdgcn_global_load_lds(
      (const __attribute__((address_space(1))) unsigned int*)g,
      (__attribute__((address_space(3))) unsigned int*)l,
      16, 0, 0);
}

// ---------------------------------------------------------------------------
// P0: zero the 1px borders of xbp and t1b + zero tof
// ---------------------------------------------------------------------------
__global__ __launch_bounds__(256) void clear_borders(
    unsigned short* __restrict__ xbp, unsigned short* __restrict__ t1b,
    float* __restrict__ tof)
{
  int i = blockIdx.x*256 + threadIdx.x;        // 58368 exact
  int q = i & 31; int pid = i >> 5;
  int b = pid / 228, j = pid % 228;
  int y, x;
  if (j < 58)       { y = 0;  x = j; }
  else if (j < 116) { y = 57; x = j - 58; }
  else { int jj = j - 116; y = 1 + (jj >> 1); x = (jj & 1) * 57; }
  size_t addr = ((size_t)(b*NHP + y)*NHP + x)*256 + q*8;
  uint4 z = make_uint4(0u,0u,0u,0u);
  *(uint4*)(xbp + addr) = z;
  *(uint4*)(t1b + addr) = z;
  int zi = i*8;                                // 56448*8 = 451584 exact
  if (zi < TOFN) {
    *(float4*)(tof + zi)     = make_float4(0.f,0.f,0.f,0.f);
    *(float4*)(tof + zi + 4) = make_float4(0.f,0.f,0.f,0.f);
  }
}

// ---------------------------------------------------------------------------
// P1: x NCHW fp32 -> xbp padded NHWC bf16 (interior only)
// ---------------------------------------------------------------------------
__global__ __launch_bounds__(256) void prep_x(
    const float* __restrict__ x, unsigned short* __restrict__ xbp)
{
  __shared__ float T[64][65];
  const int pxt  = blockIdx.x * 64;       // never crosses b (3136 = 49*64)
  const int cg   = blockIdx.y * 64;
  const int b    = pxt / NHW;
  const int rem0 = pxt % NHW;
  const int t    = threadIdx.x;
  const int pl   = t & 63;
  const int c0   = t >> 6;
  const float* src = x + (size_t)b*NCHW + rem0;
  #pragma unroll
  for (int it = 0; it < 16; ++it) {
    int c = c0 + it*4;
    T[c][pl] = src[(size_t)(cg + c)*NHW + pl];
  }
  __syncthreads();
  const int pr = t >> 5;
  const int cp = t & 31;
  #pragma unroll
  for (int it = 0; it < 8; ++it) {
    int pxl = pr + it*8;
    int rem = rem0 + pxl;
    int ho = rem / NW, wo = rem % NW;
    unsigned int pk = ((unsigned int)f2b(T[cp*2+1][pxl]) << 16) | (unsigned int)f2b(T[cp*2][pxl]);
    *(unsigned int*)(xbp + ((size_t)(b*NHP + ho + 1)*NHP + (wo + 1))*256 + cg + cp*2) = pk;
  }
}

// ---------------------------------------------------------------------------
// P2: all three weight preps in ONE kernel
// ---------------------------------------------------------------------------
__global__ __launch_bounds__(256) void prep_w_all(
    const float* __restrict__ w1, const float* __restrict__ w2,
    const float* __restrict__ ow,
    unsigned short* __restrict__ w1p, unsigned short* __restrict__ w2p,
    unsigned short* __restrict__ w3p)
{
  int i = blockIdx.x*256 + threadIdx.x;    // 1253376 exact (4896 blocks)
  if (i < 589824) {
    int co = i / 2304, r = i % 2304, k = r >> 8, ci = r & 255;
    w1p[i] = f2b(w1[((size_t)co*256 + ci)*9 + k]);
  } else if (i < 1179648) {
    int j = i - 589824;
    int co = j / 2304, r = j % 2304, k = r >> 8, ci = r & 255;
    w2p[j] = f2b(w2[((size_t)co*256 + ci)*9 + k]);
  } else {
    int j = i - 1179648;                   // < 73728
    int co = j / 2304, r = j % 2304, k = r >> 8, ci = r & 255;
    w3p[j] = (co < 18) ? f2b(ow[((size_t)co*256 + ci)*9 + k]) : (unsigned short)0;
  }
}

// ---------------------------------------------------------------------------
// GEMM1: conv3x3 + BN + ReLU -> t1b padded NHWC bf16
// BM=64 BN=256 BK=64, 512 thr = 8 waves (2M x 4N), wave tile 32x64; grid 392
// ALL staging via global_load_lds DMA (pre-swizzled source, linear LDS dest
// == round-4's swizzled LDS image). Zero staging VGPRs. LDS dbuf, 1 sync/round.
// ---------------------------------------------------------------------------
__global__ __launch_bounds__(512, 4) void gemm_conv1(
    const unsigned short* __restrict__ xbp, const unsigned short* __restrict__ w1p,
    const float* __restrict__ gam, const float* __restrict__ bet,
    const float* __restrict__ mu,  const float* __restrict__ var,
    unsigned short* __restrict__ t1b)
{
  __shared__ unsigned short SMEM[2*BUFS];    // 80KB: two of (Al 4096 | Bl 16384)

  const int bx   = blockIdx.x;
  const int nbx  = (bx & 7)*49 + (bx >> 3);   // 392 = 8*49, batch-per-XCD
  const int m0   = nbx * 64;
  const int t    = threadIdx.x;
  const int lane = t & 63;
  const int wv   = t >> 6;
  const int wvM  = wv & 1;
  const int wvN  = wv >> 1;
  const int quad = lane >> 4;
  const int l15  = lane & 15;

  // DMA lane mapping. A: wave w covers rows w*8..w*8+7; lane l -> row w*8+(l>>3),
  // sub' = l&7. Source is pre-swizzled (sub = sub' ^ (row&7)); LDS dest linear.
  const int srow = t >> 3;               // = wv*8 + (lane>>3), 0..63
  const int seg  = t & 7;                // = lane&7
  const int swz8 = ((seg ^ (srow & 7))*8);   // swizzled sub-block (shorts)
  const int px  = m0 + srow;
  const int b   = px / NHW, rem = px % NHW;
  const int ho  = rem / NW, wo = rem % NW;
  const unsigned int pbaseA = ((unsigned int)(b*NHP + ho)*NHP + wo)*256u + (unsigned int)swz8;
  // B: chunk c = wv*4+j covers rows c*8..c*8+7; row&7 = lane>>3 for all chunks
  const int rowB0 = wv*32 + (lane >> 3);
  const unsigned int bswz = (unsigned int)(((lane & 7) ^ (lane >> 3))*8);
  const int chA = wv*512;                // A LDS chunk base (shorts)

  f32x4 acc[2][4];
  #pragma unroll
  for (int i = 0; i < 2; ++i)
    #pragma unroll
    for (int j = 0; j < 4; ++j) acc[i][j] = (f32x4)(0.f);

  {   // prologue: DMA r=0 into buf0
    dma16(xbp + pbaseA, &SMEM[chA]);
    #pragma unroll
    for (int j = 0; j < 4; ++j)
      dma16(w1p + (size_t)(rowB0 + j*8)*2304 + bswz, &SMEM[4096 + (wv*4 + j)*512]);
    __syncthreads();
  }

  for (int r = 0; r < 36; ++r) {
    unsigned short* Ac = SMEM + (r & 1)*BUFS;
    unsigned short* Bc = Ac + 4096;
    unsigned short* An = SMEM + ((r + 1) & 1)*BUFS;
    unsigned short* Bn = An + 4096;
    {   // DMA r+1 into next buffer (in flight across the MFMA phase)
      const int rn = (r < 35) ? r + 1 : 35;
      const int kn = rn >> 2, cicn = rn & 3;
      const int kyn = kn/3, kxn = kn - kyn*3;
      const unsigned int koff = (unsigned int)((kyn*NHP + kxn)*256 + cicn*64);
      dma16(xbp + pbaseA + koff, &An[chA]);
      const unsigned int rb = (unsigned int)(rn*64);
      #pragma unroll
      for (int j = 0; j < 4; ++j)
        dma16(w1p + (size_t)(rowB0 + j*8)*2304 + rb + bswz, &Bn[(wv*4 + j)*512]);
    }
    // MFMA from current buffer
    #pragma unroll
    for (int kk = 0; kk < 2; ++kk) {
      const int s8 = (kk*4 + quad) ^ (l15 & 7);
      bf16x8 af[2], bfr[4];
      #pragma unroll
      for (int mt = 0; mt < 2; ++mt)
        af[mt] = *(const bf16x8*)(&Ac[(wvM*32 + mt*16 + l15)*64 + s8*8]);
      #pragma unroll
      for (int nt = 0; nt < 4; ++nt)
        bfr[nt] = *(const bf16x8*)(&Bc[(wvN*64 + nt*16 + l15)*64 + s8*8]);
      #pragma unroll
      for (int mt = 0; mt < 2; ++mt)
        #pragma unroll
        for (int nt = 0; nt < 4; ++nt)
          acc[mt][nt] = __builtin_amdgcn_mfma_f32_16x16x32_bf16(af[mt], bfr[nt], acc[mt][nt], 0, 0, 0);
    }
    __syncthreads();   // drains DMA (vmcnt 0) + makes next buffer visible
  }

  // epilogue: BN+ReLU -> per-wave bounce (32px x 72 shorts) -> padded t1b
  unsigned short* Sw = SMEM + wv*2304;
  #pragma unroll
  for (int nt = 0; nt < 4; ++nt) {
    const int co = wvN*64 + nt*16 + l15;
    const float inv  = gam[co] * rsqrtf(var[co] + EPSV);
    const float beta = bet[co] - mu[co]*inv;
    #pragma unroll
    for (int mt = 0; mt < 2; ++mt) {
      #pragma unroll
      for (int rr = 0; rr < 4; ++rr) {
        const int pxl = mt*16 + quad*4 + rr;
        float val = acc[mt][nt][rr]*inv + beta;
        val = val > 0.f ? val : 0.f;
        Sw[pxl*72 + nt*16 + l15] = f2b(val);
      }
    }
  }
  #pragma unroll
  for (int i = 0; i < 4; ++i) {
    const int pxl = (lane >> 3) + 8*i;
    const int sc  = lane & 7;
    uint4 q = *(const uint4*)(&Sw[pxl*72 + sc*8]);
    const int pg = m0 + wvM*32 + pxl;
    const int bb = pg / NHW, rm = pg % NHW;
    const int hh = rm / NW, ww = rm % NW;
    *(uint4*)(t1b + ((size_t)(bb*NHP + hh + 1)*NHP + ww + 1)*256 + wvN*64 + sc*8) = q;
  }
}

// ---------------------------------------------------------------------------
// GEMM-OFF: offset conv, split-K x4 (9 rounds each), atomicAdd into toff
// (unchanged, verified)
// ---------------------------------------------------------------------------
__global__ __launch_bounds__(256, 8) void gemm_off(
    const unsigned short* __restrict__ t1b, const unsigned short* __restrict__ w3p,
    const float* __restrict__ ob, float* __restrict__ toff)
{
  __shared__ unsigned short Al[4096];   // 64x64
  __shared__ unsigned short Bl[2048];   // 32x64

  const int bx  = blockIdx.x;
  const int nbx = (bx & 7)*49 + (bx >> 3);
  const int m0  = nbx * 64;
  const int kc = blockIdx.y;            // K chunk 0..3
  const int t    = threadIdx.x;
  const int lane = t & 63;
  const int wv   = t >> 6;
  const int quad = lane >> 4;
  const int l15  = lane & 15;

  const int arow = t >> 2;      // 0..63
  const int as4  = t & 3;
  const int axor = arow & 7;
  const int pxa  = m0 + arow;
  const int ba   = pxa / NHW, rema = pxa % NHW;
  const unsigned int pbase = ((unsigned int)(ba*NHP + rema/NW)*NHP + rema%NW)*256u;

  const int brow = t >> 3;      // 0..31
  const int bs   = t & 7;

  f32x4 acc[2];
  #pragma unroll
  for (int nt = 0; nt < 2; ++nt) {
    float init = 0.f;
    if (kc == 0) { int co = nt*16 + l15; init = (co < 18) ? ob[co] : 0.f; }
    acc[nt] = (f32x4)(init);
  }

  uint4 pA0, pA1, pB;
  {   // prefetch first round r = kc*9
    const int r = kc*9, k = r >> 2, cic = r & 3;
    const int ky = k/3, kx = k - ky*3;
    const unsigned int base = pbase + (unsigned int)((ky*NHP + kx)*256 + cic*64);
    pA0 = *(const uint4*)(t1b + base + as4*8);
    pA1 = *(const uint4*)(t1b + base + (as4+4)*8);
    pB  = *(const uint4*)(w3p + (size_t)brow*2304 + r*64 + bs*8);
  }

  for (int rr = 0; rr < 9; ++rr) {
    const int r = kc*9 + rr;
    __syncthreads();
    *(uint4*)(&Al[arow*64 + ((as4     ^ axor)*8)]) = pA0;
    *(uint4*)(&Al[arow*64 + (((as4+4) ^ axor)*8)]) = pA1;
    *(uint4*)(&Bl[brow*64 + ((bs ^ (brow & 7))*8)]) = pB;
    {
      const int rn = (rr < 8) ? r + 1 : r;
      const int kn = rn >> 2, cicn = rn & 3;
      const int kyn = kn/3, kxn = kn - kyn*3;
      const unsigned int base = pbase + (unsigned int)((kyn*NHP + kxn)*256 + cicn*64);
      pA0 = *(const uint4*)(t1b + base + as4*8);
      pA1 = *(const uint4*)(t1b + base + (as4+4)*8);
      pB  = *(const uint4*)(w3p + (size_t)brow*2304 + rn*64 + bs*8);
    }
    soft_barrier();
    #pragma unroll
    for (int kk = 0; kk < 2; ++kk) {
      const int s8 = (kk*4 + quad) ^ (l15 & 7);
      bf16x8 af = *(const bf16x8*)(&Al[(wv*16 + l15)*64 + s8*8]);
      #pragma unroll
      for (int nt = 0; nt < 2; ++nt) {
        bf16x8 bfr = *(const bf16x8*)(&Bl[(nt*16 + l15)*64 + s8*8]);
        acc[nt] = __builtin_amdgcn_mfma_f32_16x16x32_bf16(af, bfr, acc[nt], 0, 0, 0);
      }
    }
  }
  #pragma unroll
  for (int nt = 0; nt < 2; ++nt) {
    const int co = nt*16 + l15;
    if (co < 18) {
      #pragma unroll
      for (int rr2 = 0; rr2 < 4; ++rr2) {
        const int pg = m0 + wv*16 + quad*4 + rr2;
        const int bb = pg / NHW, rm = pg % NHW;
        atomicAdd(&toff[(size_t)bb*(18*NHW) + (size_t)co*NHW + rm], acc[nt][rr2]);
      }
    }
  }
}

// ---------------------------------------------------------------------------
// GEMM2: deform_conv + BN + residual + ReLU -> out NCHW fp32
// BM=64 BN=256 BK=64, 512 thr = 8 waves; B-tile via global_load_lds DMA
// (pre-swizzled source), corners via VGPR gather+pack (round-4 proven logic).
// LDS dbuf, one __syncthreads per round (drains DMA).
// ---------------------------------------------------------------------------
__global__ __launch_bounds__(512, 4) void gemm_deform(
    const unsigned short* __restrict__ t1b, const unsigned short* __restrict__ w2p,
    const float* __restrict__ toff, const float* __restrict__ xres,
    const float* __restrict__ gam, const float* __restrict__ bet,
    const float* __restrict__ mu,  const float* __restrict__ var,
    float* __restrict__ outp)
{
  __shared__ unsigned short SMEM[2*BUFS];    // 80KB

  const int bid  = blockIdx.x;
  const int nb   = (bid & 7)*49 + (bid >> 3);   // 392 = 8*49
  const int m0   = nb * 64;
  const int t    = threadIdx.x;
  const int lane = t & 63;
  const int wv   = t >> 6;
  const int wvM  = wv & 1;
  const int wvN  = wv >> 1;
  const int quad = lane >> 4;
  const int l15  = lane & 15;

  const int srow = t >> 3;     // 0..63
  const int seg  = t & 7;
  const int sxor = srow & 7;
  const int px   = m0 + srow;
  const int b    = px / NHW, rem = px % NHW;
  const int ho   = rem / NW, wo = rem % NW;
  const int obb  = b*(18*NHW) + rem;
  const unsigned int prowb = (unsigned int)(b*NHP);

  // B DMA mapping (identical LDS image to round-4's swizzled layout)
  const int rowB0 = wv*32 + (lane >> 3);
  const unsigned int bswz = (unsigned int)(((lane & 7) ^ (lane >> 3))*8);

  f32x4 acc[2][4];
  #pragma unroll
  for (int i = 0; i < 2; ++i)
    #pragma unroll
    for (int j = 0; j < 4; ++j) acc[i][j] = (f32x4)(0.f);

  // bilinear coord state for the k being issued
  unsigned int o00, o01, o10, o11;
  float w00, w01, w10, w11;
#define COORDS(KK) {                                                   \
    const int ky_ = (KK)/3, kx_ = (KK) - ky_*3;                        \
    const float offy = toff[obb + (KK)*NHW];                           \
    const float offx = toff[obb + (9+(KK))*NHW];                       \
    const float yf = (float)(ho - 1 + ky_) + offy;                     \
    const float xf = (float)(wo - 1 + kx_) + offx;                     \
    const float y0f = floorf(yf), x0f = floorf(xf);                    \
    const float ty = yf - y0f,   tx = xf - x0f;                        \
    const int y0p = (int)y0f + 1, x0p = (int)x0f + 1;                  \
    const int cy0 = min(max(y0p,   0), NHP-1);                         \
    const int cy1 = min(max(y0p+1, 0), NHP-1);                         \
    const int cx0 = min(max(x0p,   0), NHP-1);                         \
    const int cx1 = min(max(x0p+1, 0), NHP-1);                         \
    w00 = (1.f-ty)*(1.f-tx);  w01 = (1.f-ty)*tx;                       \
    w10 = ty*(1.f-tx);        w11 = ty*tx;                             \
    o00 = ((prowb + cy0)*NHP + cx0)*256u + seg*8u;                     \
    o01 = ((prowb + cy0)*NHP + cx1)*256u + seg*8u;                     \
    o10 = ((prowb + cy1)*NHP + cx0)*256u + seg*8u;                     \
    o11 = ((prowb + cy1)*NHP + cx1)*256u + seg*8u;                     \
  }

// bilinear-combine 4 corner uint4 -> one uint4 row -> LDS dest (swizzled write)
#define PACKW(DST) {                                                            \
    uint4 res;                                                                  \
    { float a0 = w00*blo(pc00.x) + w01*blo(pc01.x) + w10*blo(pc10.x) + w11*blo(pc11.x); \
      float a1 = w00*bhi(pc00.x) + w01*bhi(pc01.x) + w10*bhi(pc10.x) + w11*bhi(pc11.x); \
      res.x = pack_trunc(a0, a1); }                                             \
    { float a0 = w00*blo(pc00.y) + w01*blo(pc01.y) + w10*blo(pc10.y) + w11*blo(pc11.y); \
      float a1 = w00*bhi(pc00.y) + w01*bhi(pc01.y) + w10*bhi(pc10.y) + w11*bhi(pc11.y); \
      res.y = pack_trunc(a0, a1); }                                             \
    { float a0 = w00*blo(pc00.z) + w01*blo(pc01.z) + w10*blo(pc10.z) + w11*blo(pc11.z); \
      float a1 = w00*bhi(pc00.z) + w01*bhi(pc01.z) + w10*bhi(pc10.z) + w11*bhi(pc11.z); \
      res.z = pack_trunc(a0, a1); }                                             \
    { float a0 = w00*blo(pc00.w) + w01*blo(pc01.w) + w10*blo(pc10.w) + w11*blo(pc11.w); \
      float a1 = w00*bhi(pc00.w) + w01*bhi(pc01.w) + w10*bhi(pc10.w) + w11*bhi(pc11.w); \
      res.w = pack_trunc(a0, a1); }                                             \
    *(uint4*)(&(DST)[srow*64 + ((seg ^ sxor)*8)]) = res;                        \
  }

#define ISSUEC(RN) {                                                           \
    const unsigned int cio_ = (unsigned int)(((RN) & 3)*64);                   \
    pc00 = *(const uint4*)(t1b + o00 + cio_);                                  \
    pc01 = *(const uint4*)(t1b + o01 + cio_);                                  \
    pc10 = *(const uint4*)(t1b + o10 + cio_);                                  \
    pc11 = *(const uint4*)(t1b + o11 + cio_);                                  \
  }

  uint4 pc00, pc01, pc10, pc11;

  COORDS(0);
  {   // prologue: corners(0) -> pack into buf0; DMA B(0) -> buf0; issue corners(1)
    ISSUEC(0);
    #pragma unroll
    for (int j = 0; j < 4; ++j)
      dma16(w2p + (size_t)(rowB0 + j*8)*2304 + bswz, &SMEM[4096 + (wv*4 + j)*512]);
    PACKW(SMEM);
    ISSUEC(1);
    __syncthreads();
  }

  for (int r = 0; r < 36; ++r) {
    unsigned short* Ac = SMEM + (r & 1)*BUFS;
    unsigned short* Bc = Ac + 4096;
    unsigned short* An = SMEM + ((r + 1) & 1)*BUFS;
    unsigned short* Bn = An + 4096;
    // pack prefetched corners(r+1) -> next A buffer (weights for k=(r+1)>>2 live)
    PACKW(An);
    {   // DMA B(r+1) -> next B buffer
      const int rnB = (r < 35) ? r + 1 : 35;
      const unsigned int rb = (unsigned int)(rnB*64);
      #pragma unroll
      for (int j = 0; j < 4; ++j)
        dma16(w2p + (size_t)(rowB0 + j*8)*2304 + rb + bswz, &Bn[(wv*4 + j)*512]);
    }
    // coords for the k of round r+2 (AFTER pack used old weights)
    if ((r & 3) == 2 && r < 34) COORDS((r + 2) >> 2);
    {   // issue corners(r+2) into regs (latency hidden by MFMA + drained at barrier)
      const int rn = (r < 34) ? r + 2 : 35;
      ISSUEC(rn);
    }
    // MFMA from current buffer
    #pragma unroll
    for (int kk = 0; kk < 2; ++kk) {
      const int s8 = (kk*4 + quad) ^ (l15 & 7);
      bf16x8 af[2], bfr[4];
      #pragma unroll
      for (int mt = 0; mt < 2; ++mt)
        af[mt] = *(const bf16x8*)(&Ac[(wvM*32 + mt*16 + l15)*64 + s8*8]);
      #pragma unroll
      for (int nt = 0; nt < 4; ++nt)
        bfr[nt] = *(const bf16x8*)(&Bc[(wvN*64 + nt*16 + l15)*64 + s8*8]);
      #pragma unroll
      for (int mt = 0; mt < 2; ++mt)
        #pragma unroll
        for (int nt = 0; nt < 4; ++nt)
          acc[mt][nt] = __builtin_amdgcn_mfma_f32_16x16x32_bf16(af[mt], bfr[nt], acc[mt][nt], 0, 0, 0);
    }
    __syncthreads();   // drains B-DMA + corner loads, publishes next buffers
  }
#undef ISSUEC
#undef PACKW
#undef COORDS

  // epilogue: per-wave f32 bounce (32px x 33), 2 co-halves -> coalesced NCHW
  float* Sl = (float*)SMEM + wv*1056;
  const int pxl_r = lane & 31;
  const int csel  = lane >> 5;
  const int pg    = m0 + wvM*32 + pxl_r;
  const int bo    = pg / NHW, remo = pg % NHW;
  const size_t obase = (size_t)bo*NCHW + remo;
  #pragma unroll
  for (int h = 0; h < 2; ++h) {
    #pragma unroll
    for (int nt2 = 0; nt2 < 2; ++nt2) {
      const int nt = h*2 + nt2;
      #pragma unroll
      for (int mt = 0; mt < 2; ++mt) {
        #pragma unroll
        for (int rr = 0; rr < 4; ++rr) {
          const int pxl = mt*16 + quad*4 + rr;
          Sl[pxl*33 + nt2*16 + l15] = acc[mt][nt][rr];
        }
      }
    }
    #pragma unroll
    for (int j = 0; j < 16; ++j) {
      const int col = csel*16 + j;
      const int co  = wvN*64 + h*32 + col;
      const float inv  = gam[co] * rsqrtf(var[co] + EPSV);
      const float beta = bet[co] - mu[co]*inv;
      const size_t off = obase + (size_t)co*NHW;
      float val = Sl[pxl_r*33 + col];
      float o = val*inv + beta + xres[off];
      outp[off] = o > 0.f ? o : 0.f;
    }
  }
}

extern "C" void kernel_launch(void* const* d_in, const int* in_sizes, int n_in,
                              void* d_out, int out_size, void* d_ws, size_t ws_size,
                              hipStream_t stream) {
  const float* x   = (const float*)d_in[0];
  const float* w1  = (const float*)d_in[1];
  const float* g1  = (const float*)d_in[2];
  const float* b1  = (const float*)d_in[3];
  const float* m1  = (const float*)d_in[4];
  const float* v1  = (const float*)d_in[5];
  const float* ow  = (const float*)d_in[6];
  const float* ob  = (const float*)d_in[7];
  const float* w2  = (const float*)d_in[8];
  const float* g2  = (const float*)d_in[9];
  const float* b2  = (const float*)d_in[10];
  const float* m2  = (const float*)d_in[11];
  const float* v2  = (const float*)d_in[12];
  float* out = (float*)d_out;

  const size_t PADSZ = (size_t)NB*NHP*NHP*256;
  unsigned short* xbp = (unsigned short*)d_ws;
  unsigned short* t1b = xbp + PADSZ;
  float*          tof = (float*)(t1b + PADSZ);
  unsigned short* w1p = (unsigned short*)(tof + (size_t)NB*18*NHW);
  unsigned short* w2p = w1p + (size_t)589824;
  unsigned short* w3p = w2p + (size_t)589824;

  clear_borders<<<228, 256, 0, stream>>>(xbp, t1b, tof);
  dim3 gp(392, 4, 1);
  prep_x<<<gp, 256, 0, stream>>>(x, xbp);
  prep_w_all<<<4896, 256, 0, stream>>>(w1, w2, ow, w1p, w2p, w3p);

  gemm_conv1<<<392, 512, 0, stream>>>(xbp, w1p, g1, b1, m1, v1, t1b);
  dim3 go(392, 4, 1);
  gemm_off<<<go, 256, 0, stream>>>(t1b, w3p, ob, tof);
  gemm_deform<<<392, 512, 0, stream>>>(t1b, w2p, tof, x, g2, b2, m2, v2, out);
}